// Round 4
// baseline (1153.995 us; speedup 1.0000x reference)
//
#include <hip/hip_runtime.h>

#define NN 20000
#define NE 640000
#define NF 128
#define EF 32
#define HD 128
#define NL 3

typedef __bf16 bf16x8 __attribute__((ext_vector_type(8)));
typedef float f32x4 __attribute__((ext_vector_type(4)));

constexpr int BE = 64;          // edges per k_message block
constexpr int KA = 2 * NF + EF; // 288
constexpr int SA2 = 168;        // sA row stride (bf16), 160 cols used
constexpr int STP = 136;        // sT / sM row stride (bf16)
constexpr int KU = NF + HD;     // 256
constexpr int SUP = 264;        // sU row stride (bf16), k_update
constexpr int SXP = 132;        // sX row stride (f32)
constexpr int NB_MSG = NE / BE; // 10000
constexpr int CPX = NB_MSG / 8; // 1250

// ================= fused pre: hist + weight repack + node embed =================
// blocks [0,2500): histogram of dst
// blocks [2500,2564): weight repack fp32 -> bf16 [(k>>3)][n][k&7]
// blocks [2564,12564): node embedding, 2 nodes per block
__global__ __launch_bounds__(256) void k_pre(
    const int* __restrict__ ei, int* __restrict__ cnt,
    const float* __restrict__ mW1, const float* __restrict__ mW2,
    const float* __restrict__ uW1, const float* __restrict__ uW2,
    const float* __restrict__ Wo,
    __bf16* __restrict__ W1f, __bf16* __restrict__ W2f,
    __bf16* __restrict__ U1f, __bf16* __restrict__ U2f,
    __bf16* __restrict__ Wof,
    const float* __restrict__ coords, const float* __restrict__ Wn,
    const float* __restrict__ bn, float* __restrict__ h, __bf16* __restrict__ hbf)
{
    const int b = blockIdx.x;
    const int tid = threadIdx.x;
    if (b < 2500) {
        const int e = b * 256 + tid;
        atomicAdd(&cnt[ei[NE + e]], 1);
        return;
    }
    if (b < 2564) {
        const int t = (b - 2500) * 256 + tid;
        const int stride = 64 * 256;
        for (int i = t; i < NL * KA * HD; i += stride) {
            const int l = i / (KA * HD);
            const int r = i - l * (KA * HD);
            const int k = r >> 7, n = r & 127;
            W1f[(size_t)l * KA * HD + ((((k >> 3) * HD) + n) << 3) + (k & 7)] = (__bf16)mW1[i];
        }
        for (int i = t; i < NL * HD * HD; i += stride) {
            const int l = i / (HD * HD);
            const int r = i - l * (HD * HD);
            const int k = r >> 7, n = r & 127;
            W2f[(size_t)l * HD * HD + ((((k >> 3) * HD) + n) << 3) + (k & 7)] = (__bf16)mW2[i];
        }
        for (int i = t; i < NL * KU * HD; i += stride) {
            const int l = i / (KU * HD);
            const int r = i - l * (KU * HD);
            const int k = r >> 7, n = r & 127;
            U1f[(size_t)l * KU * HD + ((((k >> 3) * HD) + n) << 3) + (k & 7)] = (__bf16)uW1[i];
        }
        for (int i = t; i < NL * HD * NF; i += stride) {
            const int l = i / (HD * NF);
            const int r = i - l * (HD * NF);
            const int k = r >> 7, n = r & 127;
            U2f[(size_t)l * HD * NF + ((((k >> 3) * NF) + n) << 3) + (k & 7)] = (__bf16)uW2[i];
        }
        for (int i = t; i < NF * HD; i += stride) {
            const int k = i >> 7, n = i & 127;
            Wof[((((k >> 3) * HD) + n) << 3) + (k & 7)] = (__bf16)Wo[i];
        }
        return;
    }
    // node embedding: 2 nodes per block
    __shared__ float sc[12];
    const int n0 = (b - 2564) * 2;
    if (tid < 12) sc[tid] = coords[n0 * 6 + tid];
    __syncthreads();
    const int node = n0 + (tid >> 7);
    const int f = tid & 127;
    const int cb = (tid >> 7) * 6;
    float acc = bn[f];
#pragma unroll
    for (int k = 0; k < 6; ++k) acc = fmaf(sc[cb + k], Wn[k * NF + f], acc);
    h[(size_t)node * NF + f] = acc;
    hbf[(size_t)node * NF + f] = (__bf16)acc;
}

// ================= exclusive scan of counts =================
__global__ __launch_bounds__(1024) void k_scan(const int* __restrict__ cnt, int* __restrict__ pos)
{
    __shared__ int ls[1024];
    const int tid = threadIdx.x;
    const int C = 20;
    const int base = tid * C;
    int s = 0;
#pragma unroll
    for (int i = 0; i < C; ++i) {
        const int idx = base + i;
        if (idx < NN) s += cnt[idx];
    }
    ls[tid] = s;
    __syncthreads();
    for (int off = 1; off < 1024; off <<= 1) {
        const int v = (tid >= off) ? ls[tid - off] : 0;
        __syncthreads();
        ls[tid] += v;
        __syncthreads();
    }
    int p = tid ? ls[tid - 1] : 0;
#pragma unroll
    for (int i = 0; i < C; ++i) {
        const int idx = base + i;
        if (idx < NN) { pos[idx] = p; p += cnt[idx]; }
    }
}

// ================= scatter edges to sorted order + fused edge embedding =================
__global__ __launch_bounds__(256) void k_scatter_embed(
    const int* __restrict__ ei, int* __restrict__ pos,
    const float* __restrict__ dist, const float* __restrict__ We,
    const float* __restrict__ be,
    int* __restrict__ srcS, int* __restrict__ dstS, __bf16* __restrict__ ebfS)
{
    __shared__ float sW[32][33];
    __shared__ float sbe[32];
    const int tid = threadIdx.x;
    for (int i = tid; i < 1024; i += 256) sW[i >> 5][i & 31] = We[i];
    if (tid < 32) sbe[tid] = be[tid];
    __syncthreads();
    const int e = blockIdx.x * 256 + tid;
    if (e >= NE) return;
    const int d = ei[NE + e];
    const int p = atomicAdd(&pos[d], 1);
    srcS[p] = ei[e];
    dstS[p] = d;
    // edge embedding: e_row @ We + be
    float dr[32];
    const float4* dp = reinterpret_cast<const float4*>(dist + (size_t)e * EF);
#pragma unroll
    for (int q = 0; q < 8; ++q) {
        const float4 v = dp[q];
        dr[q * 4 + 0] = v.x; dr[q * 4 + 1] = v.y; dr[q * 4 + 2] = v.z; dr[q * 4 + 3] = v.w;
    }
#pragma unroll
    for (int jg = 0; jg < 4; ++jg) {
        union { __bf16 b[8]; uint4 u; } pk;
#pragma unroll
        for (int jj = 0; jj < 8; ++jj) {
            const int j = jg * 8 + jj;
            float acc = sbe[j];
#pragma unroll
            for (int q = 0; q < 32; ++q) acc = fmaf(dr[q], sW[q][j], acc);
            pk.b[jj] = (__bf16)acc;
        }
        *reinterpret_cast<uint4*>(ebfS + (size_t)p * EF + jg * 8) = pk.u;
    }
}

// ================= fused edge message (bf16 MFMA, two-pass K) + segmented scatter =================
__global__ __launch_bounds__(256, 7) void k_message(
    const __bf16* __restrict__ hbf,
    const int* __restrict__ srcS, const int* __restrict__ dstS,
    const __bf16* __restrict__ ebfS,
    const __bf16* __restrict__ W1f, const float* __restrict__ b1,
    const __bf16* __restrict__ W2f, const float* __restrict__ b2,
    float* __restrict__ agg)
{
    __shared__ __attribute__((aligned(16))) __bf16 R[BE * SA2]; // sA(64x168) -> sT(64x136) -> sM(64x136) overlay
    __shared__ int s_src[BE], s_dst[BE];
    __bf16* sA = R;
    __bf16* sT = R;
    __bf16* sM = R;

    const int tid = threadIdx.x;
    const int bid = (blockIdx.x & 7) * CPX + (blockIdx.x >> 3); // XCD chunk swizzle
    const int e0 = bid * BE;
    const int w = tid >> 6;
    const int lane = tid & 63;
    const int m16 = lane & 15;
    const int kb = lane >> 4;
    const int n0 = w * 32;

    if (tid < BE) {
        s_src[tid] = srcS[e0 + tid];
        s_dst[tid] = dstS[e0 + tid];
    }

    // register-resident B fragments for GEMM1 (all 9 K-blocks)
    bf16x8 bf1[9][2];
#pragma unroll
    for (int k9 = 0; k9 < 9; ++k9)
#pragma unroll
        for (int nf = 0; nf < 2; ++nf)
            bf1[k9][nf] = *reinterpret_cast<const bf16x8*>(
                W1f + ((((k9 * 4 + kb) * HD) + n0 + nf * 16 + m16) << 3));

    __syncthreads();

    // ---- gather pass 1: sA[row][0:128] = h[src], sA[row][128:160] = e ----
#pragma unroll
    for (int it = 0; it < 4; ++it) {
        const int c = tid + it * 256;
        const int row = c >> 4, off = c & 15;
        *reinterpret_cast<uint4*>(&sA[row * SA2 + off * 8]) =
            *reinterpret_cast<const uint4*>(hbf + (size_t)s_src[row] * NF + off * 8);
    }
    {
        const int row = tid >> 2, off = tid & 3;
        *reinterpret_cast<uint4*>(&sA[row * SA2 + NF + off * 8]) =
            *reinterpret_cast<const uint4*>(ebfS + (size_t)(e0 + row) * EF + off * 8);
    }
    __syncthreads();

    // ---- GEMM1 pass A: K-blocks {0,1,2,3,8} (src cols 0..127, e cols 128..159) ----
    f32x4 acc1[4][2];
#pragma unroll
    for (int mt = 0; mt < 4; ++mt)
#pragma unroll
        for (int nf = 0; nf < 2; ++nf) acc1[mt][nf] = (f32x4){0.f, 0.f, 0.f, 0.f};

    __builtin_amdgcn_s_setprio(1);
#pragma unroll
    for (int k5 = 0; k5 < 5; ++k5) {
        const int wb = (k5 < 4) ? k5 : 8;
#pragma unroll
        for (int mt = 0; mt < 4; ++mt) {
            const bf16x8 a = *reinterpret_cast<const bf16x8*>(&sA[(mt * 16 + m16) * SA2 + k5 * 32 + kb * 8]);
            acc1[mt][0] = __builtin_amdgcn_mfma_f32_16x16x32_bf16(a, bf1[wb][0], acc1[mt][0], 0, 0, 0);
            acc1[mt][1] = __builtin_amdgcn_mfma_f32_16x16x32_bf16(a, bf1[wb][1], acc1[mt][1], 0, 0, 0);
        }
    }
    __builtin_amdgcn_s_setprio(0);
    __syncthreads(); // pass-1 sA reads done

    // ---- gather pass 2: sA[row][0:128] = h[dst] ----
#pragma unroll
    for (int it = 0; it < 4; ++it) {
        const int c = tid + it * 256;
        const int row = c >> 4, off = c & 15;
        *reinterpret_cast<uint4*>(&sA[row * SA2 + off * 8]) =
            *reinterpret_cast<const uint4*>(hbf + (size_t)s_dst[row] * NF + off * 8);
    }

    // B fragments for GEMM2 (independent global loads, overlap gather latency)
    bf16x8 bf2[4][2];
#pragma unroll
    for (int k4 = 0; k4 < 4; ++k4)
#pragma unroll
        for (int nf = 0; nf < 2; ++nf)
            bf2[k4][nf] = *reinterpret_cast<const bf16x8*>(
                W2f + ((((k4 * 4 + kb) * HD) + n0 + nf * 16 + m16) << 3));
    __syncthreads();

    // ---- GEMM1 pass B: K-blocks {4,5,6,7} (dst cols 0..127) ----
    __builtin_amdgcn_s_setprio(1);
#pragma unroll
    for (int k4 = 0; k4 < 4; ++k4) {
#pragma unroll
        for (int mt = 0; mt < 4; ++mt) {
            const bf16x8 a = *reinterpret_cast<const bf16x8*>(&sA[(mt * 16 + m16) * SA2 + k4 * 32 + kb * 8]);
            acc1[mt][0] = __builtin_amdgcn_mfma_f32_16x16x32_bf16(a, bf1[4 + k4][0], acc1[mt][0], 0, 0, 0);
            acc1[mt][1] = __builtin_amdgcn_mfma_f32_16x16x32_bf16(a, bf1[4 + k4][1], acc1[mt][1], 0, 0, 0);
        }
    }
    __builtin_amdgcn_s_setprio(0);
    __syncthreads(); // pass-2 sA reads done

    // ---- sT = relu(acc1 + b1) ----
    {
        const float b1a = b1[n0 + m16];
        const float b1b = b1[n0 + 16 + m16];
#pragma unroll
        for (int mt = 0; mt < 4; ++mt) {
#pragma unroll
            for (int reg = 0; reg < 4; ++reg) {
                const int erow = mt * 16 + kb * 4 + reg;
                sT[erow * STP + n0 + m16] = (__bf16)fmaxf(acc1[mt][0][reg] + b1a, 0.f);
                sT[erow * STP + n0 + 16 + m16] = (__bf16)fmaxf(acc1[mt][1][reg] + b1b, 0.f);
            }
        }
    }
    __syncthreads();

    // ---- GEMM2 ----
    f32x4 acc2[4][2];
#pragma unroll
    for (int mt = 0; mt < 4; ++mt)
#pragma unroll
        for (int nf = 0; nf < 2; ++nf) acc2[mt][nf] = (f32x4){0.f, 0.f, 0.f, 0.f};

    __builtin_amdgcn_s_setprio(1);
#pragma unroll
    for (int k4 = 0; k4 < 4; ++k4) {
#pragma unroll
        for (int mt = 0; mt < 4; ++mt) {
            const bf16x8 a = *reinterpret_cast<const bf16x8*>(&sT[(mt * 16 + m16) * STP + k4 * 32 + kb * 8]);
            acc2[mt][0] = __builtin_amdgcn_mfma_f32_16x16x32_bf16(a, bf2[k4][0], acc2[mt][0], 0, 0, 0);
            acc2[mt][1] = __builtin_amdgcn_mfma_f32_16x16x32_bf16(a, bf2[k4][1], acc2[mt][1], 0, 0, 0);
        }
    }
    __builtin_amdgcn_s_setprio(0);
    __syncthreads(); // sT reads done

    // ---- sM = acc2 + b2 (bf16) ----
    {
        const float b2a = b2[n0 + m16];
        const float b2b = b2[n0 + 16 + m16];
#pragma unroll
        for (int mt = 0; mt < 4; ++mt) {
#pragma unroll
            for (int reg = 0; reg < 4; ++reg) {
                const int erow = mt * 16 + kb * 4 + reg;
                sM[erow * STP + n0 + m16] = (__bf16)(acc2[mt][0][reg] + b2a);
                sM[erow * STP + n0 + 16 + m16] = (__bf16)(acc2[mt][1][reg] + b2b);
            }
        }
    }
    __syncthreads();

    // ---- segmented reduction over dst-sorted rows ----
    {
        const int col = tid & 127;
        const int r0 = (tid >> 7) * 32;
        int cur = s_dst[r0];
        float s = (float)sM[r0 * STP + col];
#pragma unroll
        for (int r = r0 + 1; r < r0 + 32; ++r) {
            const int d2 = s_dst[r];
            const float v = (float)sM[r * STP + col];
            if (d2 != cur) {
                atomicAdd(&agg[(size_t)cur * HD + col], s);
                cur = d2;
                s = v;
            } else {
                s += v;
            }
        }
        atomicAdd(&agg[(size_t)cur * HD + col], s);
    }
}

// ================= node update MLP (bf16 MFMA) + residual + LayerNorm, 32-node tiles =================
__global__ __launch_bounds__(256, 8) void k_update(
    float* __restrict__ h, float* __restrict__ agg,
    const __bf16* __restrict__ U1f, const float* __restrict__ b1,
    const __bf16* __restrict__ U2f, const float* __restrict__ b2,
    const float* __restrict__ g, const float* __restrict__ bln,
    __bf16* __restrict__ hbf)
{
    __shared__ __attribute__((aligned(16))) __bf16 R[32 * SUP]; // sU(32x264) / sT(32x136) / sX f32(32x132)
    __bf16* sU = R;
    __bf16* sT = R;
    float* sX = (float*)R;

    const int tid = threadIdx.x;
    const int n0 = blockIdx.x * 32;
    const int w = tid >> 6;
    const int lane = tid & 63;
    const int m16 = lane & 15;
    const int kb = lane >> 4;
    const int nw0 = w * 32;

    // gather u_in = [hbf | agg->bf16]; zero agg after reading (for next layer)
#pragma unroll
    for (int it = 0; it < 2; ++it) {
        const int c = tid + it * 256;
        const int row = c >> 4, off = c & 15;
        *reinterpret_cast<uint4*>(&sU[row * SUP + off * 8]) =
            *reinterpret_cast<const uint4*>(hbf + (size_t)(n0 + row) * NF + off * 8);
    }
#pragma unroll
    for (int it = 0; it < 4; ++it) {
        const int c = tid + it * 256;
        const int row = c >> 5, off = c & 31;
        float* ap = agg + (size_t)(n0 + row) * HD + off * 4;
        const float4 v = *reinterpret_cast<const float4*>(ap);
        union { __bf16 b[4]; uint2 u; } cv;
        cv.b[0] = (__bf16)v.x; cv.b[1] = (__bf16)v.y; cv.b[2] = (__bf16)v.z; cv.b[3] = (__bf16)v.w;
        *reinterpret_cast<uint2*>(&sU[row * SUP + NF + off * 4]) = cv.u;
        *reinterpret_cast<float4*>(ap) = (float4){0.f, 0.f, 0.f, 0.f};
    }
    __syncthreads();

    // GEMM1 (K=256): wave owns 32 rows x 32 cols
    f32x4 acc1[2][2];
#pragma unroll
    for (int mt = 0; mt < 2; ++mt)
#pragma unroll
        for (int nf = 0; nf < 2; ++nf) acc1[mt][nf] = (f32x4){0.f, 0.f, 0.f, 0.f};
#pragma unroll
    for (int k8 = 0; k8 < 8; ++k8) {
        const bf16x8 bA = *reinterpret_cast<const bf16x8*>(U1f + ((((k8 * 4 + kb) * HD) + nw0 + m16) << 3));
        const bf16x8 bB = *reinterpret_cast<const bf16x8*>(U1f + ((((k8 * 4 + kb) * HD) + nw0 + 16 + m16) << 3));
#pragma unroll
        for (int mt = 0; mt < 2; ++mt) {
            const bf16x8 a = *reinterpret_cast<const bf16x8*>(&sU[(mt * 16 + m16) * SUP + k8 * 32 + kb * 8]);
            acc1[mt][0] = __builtin_amdgcn_mfma_f32_16x16x32_bf16(a, bA, acc1[mt][0], 0, 0, 0);
            acc1[mt][1] = __builtin_amdgcn_mfma_f32_16x16x32_bf16(a, bB, acc1[mt][1], 0, 0, 0);
        }
    }
    __syncthreads();

    {
        const float b1a = b1[nw0 + m16];
        const float b1b = b1[nw0 + 16 + m16];
#pragma unroll
        for (int mt = 0; mt < 2; ++mt) {
#pragma unroll
            for (int reg = 0; reg < 4; ++reg) {
                const int erow = mt * 16 + kb * 4 + reg;
                sT[erow * STP + nw0 + m16] = (__bf16)fmaxf(acc1[mt][0][reg] + b1a, 0.f);
                sT[erow * STP + nw0 + 16 + m16] = (__bf16)fmaxf(acc1[mt][1][reg] + b1b, 0.f);
            }
        }
    }
    __syncthreads();

    // GEMM2 (K=128)
    f32x4 acc2[2][2];
#pragma unroll
    for (int mt = 0; mt < 2; ++mt)
#pragma unroll
        for (int nf = 0; nf < 2; ++nf) acc2[mt][nf] = (f32x4){0.f, 0.f, 0.f, 0.f};
#pragma unroll
    for (int k4 = 0; k4 < 4; ++k4) {
        const bf16x8 bA = *reinterpret_cast<const bf16x8*>(U2f + ((((k4 * 4 + kb) * NF) + nw0 + m16) << 3));
        const bf16x8 bB = *reinterpret_cast<const bf16x8*>(U2f + ((((k4 * 4 + kb) * NF) + nw0 + 16 + m16) << 3));
#pragma unroll
        for (int mt = 0; mt < 2; ++mt) {
            const bf16x8 a = *reinterpret_cast<const bf16x8*>(&sT[(mt * 16 + m16) * STP + k4 * 32 + kb * 8]);
            acc2[mt][0] = __builtin_amdgcn_mfma_f32_16x16x32_bf16(a, bA, acc2[mt][0], 0, 0, 0);
            acc2[mt][1] = __builtin_amdgcn_mfma_f32_16x16x32_bf16(a, bB, acc2[mt][1], 0, 0, 0);
        }
    }
    __syncthreads();

    // residual -> sX (f32)
    {
        const float b2a = b2[nw0 + m16];
        const float b2b = b2[nw0 + 16 + m16];
#pragma unroll
        for (int mt = 0; mt < 2; ++mt) {
#pragma unroll
            for (int reg = 0; reg < 4; ++reg) {
                const int erow = mt * 16 + kb * 4 + reg;
                const size_t base = (size_t)(n0 + erow) * NF;
                sX[erow * SXP + nw0 + m16] = h[base + nw0 + m16] + acc2[mt][0][reg] + b2a;
                sX[erow * SXP + nw0 + 16 + m16] = h[base + nw0 + 16 + m16] + acc2[mt][1][reg] + b2b;
            }
        }
    }
    __syncthreads();

    // LayerNorm: 8 lanes per node
    {
        const int i = tid >> 3, j = tid & 7;
        float s = 0.f, s2 = 0.f;
#pragma unroll
        for (int t = 0; t < 16; ++t) {
            const float x = sX[i * SXP + j + 8 * t];
            s += x; s2 = fmaf(x, x, s2);
        }
        s += __shfl_xor(s, 1, 64);  s2 += __shfl_xor(s2, 1, 64);
        s += __shfl_xor(s, 2, 64);  s2 += __shfl_xor(s2, 2, 64);
        s += __shfl_xor(s, 4, 64);  s2 += __shfl_xor(s2, 4, 64);
        const float mu = s * (1.f / NF);
        const float var = s2 * (1.f / NF) - mu * mu;
        const float rs = rsqrtf(var + 1e-5f);
        const size_t base = (size_t)(n0 + i) * NF;
#pragma unroll
        for (int t = 0; t < 16; ++t) {
            const int col = j + 8 * t;
            const float v = (sX[i * SXP + col] - mu) * rs * g[col] + bln[col];
            h[base + col] = v;
            hbf[base + col] = (__bf16)v;
        }
    }
}

// ================= output projection (bf16 MFMA) =================
__global__ __launch_bounds__(256, 4) void k_out(
    const __bf16* __restrict__ hbf, const __bf16* __restrict__ Wof,
    const float* __restrict__ bo, float* __restrict__ out)
{
    __shared__ __attribute__((aligned(16))) __bf16 sH[64 * STP];
    const int tid = threadIdx.x;
    const int n0 = blockIdx.x * 64;
    const int w = tid >> 6;
    const int lane = tid & 63;
    const int m16 = lane & 15;
    const int kb = lane >> 4;
    const int nw0 = w * 32;

#pragma unroll
    for (int it = 0; it < 4; ++it) {
        const int c = tid + it * 256;
        const int row = c >> 4, off = c & 15;
        const int node = min(n0 + row, NN - 1);
        *reinterpret_cast<uint4*>(&sH[row * STP + off * 8]) =
            *reinterpret_cast<const uint4*>(hbf + (size_t)node * NF + off * 8);
    }
    __syncthreads();

    f32x4 acc[4][2];
#pragma unroll
    for (int mt = 0; mt < 4; ++mt)
#pragma unroll
        for (int nf = 0; nf < 2; ++nf) acc[mt][nf] = (f32x4){0.f, 0.f, 0.f, 0.f};
#pragma unroll
    for (int k4 = 0; k4 < 4; ++k4) {
        const bf16x8 bA = *reinterpret_cast<const bf16x8*>(Wof + ((((k4 * 4 + kb) * HD) + nw0 + m16) << 3));
        const bf16x8 bB = *reinterpret_cast<const bf16x8*>(Wof + ((((k4 * 4 + kb) * HD) + nw0 + 16 + m16) << 3));
#pragma unroll
        for (int mt = 0; mt < 4; ++mt) {
            const bf16x8 a = *reinterpret_cast<const bf16x8*>(&sH[(mt * 16 + m16) * STP + k4 * 32 + kb * 8]);
            acc[mt][0] = __builtin_amdgcn_mfma_f32_16x16x32_bf16(a, bA, acc[mt][0], 0, 0, 0);
            acc[mt][1] = __builtin_amdgcn_mfma_f32_16x16x32_bf16(a, bB, acc[mt][1], 0, 0, 0);
        }
    }
    const float boa = bo[nw0 + m16];
    const float bob = bo[nw0 + 16 + m16];
#pragma unroll
    for (int mt = 0; mt < 4; ++mt) {
#pragma unroll
        for (int reg = 0; reg < 4; ++reg) {
            const int erow = mt * 16 + kb * 4 + reg;
            const int node = n0 + erow;
            if (node < NN) {
                out[(size_t)node * HD + nw0 + m16] = acc[mt][0][reg] + boa;
                out[(size_t)node * HD + nw0 + 16 + m16] = acc[mt][1][reg] + bob;
            }
        }
    }
}

extern "C" void kernel_launch(void* const* d_in, const int* in_sizes, int n_in,
                              void* d_out, int out_size, void* d_ws, size_t ws_size,
                              hipStream_t stream)
{
    const float* coords = (const float*)d_in[0];
    const int* ei       = (const int*)d_in[1];
    const float* dist   = (const float*)d_in[2];
    const float* Wn  = (const float*)d_in[3];
    const float* bn  = (const float*)d_in[4];
    const float* We  = (const float*)d_in[5];
    const float* be  = (const float*)d_in[6];
    const float* mW1 = (const float*)d_in[7];
    const float* mb1 = (const float*)d_in[8];
    const float* mW2 = (const float*)d_in[9];
    const float* mb2 = (const float*)d_in[10];
    const float* uW1 = (const float*)d_in[11];
    const float* ub1 = (const float*)d_in[12];
    const float* uW2 = (const float*)d_in[13];
    const float* ub2 = (const float*)d_in[14];
    const float* lng = (const float*)d_in[15];
    const float* lnb = (const float*)d_in[16];
    const float* Wo  = (const float*)d_in[17];
    const float* bo  = (const float*)d_in[18];

    char* p = (char*)d_ws;
    float* h   = (float*)p; p += (size_t)NN * NF * 4;
    float* agg = (float*)p; p += (size_t)NN * NF * 4;
    __bf16* hbf  = (__bf16*)p; p += (size_t)NN * NF * 2;
    __bf16* ebfS = (__bf16*)p; p += (size_t)NE * EF * 2;
    __bf16* W1f = (__bf16*)p; p += (size_t)NL * KA * HD * 2;
    __bf16* W2f = (__bf16*)p; p += (size_t)NL * HD * HD * 2;
    __bf16* U1f = (__bf16*)p; p += (size_t)NL * KU * HD * 2;
    __bf16* U2f = (__bf16*)p; p += (size_t)NL * HD * NF * 2;
    __bf16* Wof = (__bf16*)p; p += (size_t)NF * HD * 2;
    int* cnt  = (int*)p; p += (size_t)NN * 4;
    int* pos  = (int*)p; p += (size_t)NN * 4;
    int* srcS = (int*)p; p += (size_t)NE * 4;
    int* dstS = (int*)p; p += (size_t)NE * 4;

    hipMemsetAsync(cnt, 0, (size_t)NN * 4, stream);
    hipMemsetAsync(agg, 0, (size_t)NN * NF * sizeof(float), stream);

    // hist + weight repack + node embed (fused)
    k_pre<<<2564 + NN / 2, 256, 0, stream>>>(ei, cnt, mW1, mW2, uW1, uW2, Wo,
                                             W1f, W2f, U1f, U2f, Wof,
                                             coords, Wn, bn, h, hbf);
    k_scan<<<1, 1024, 0, stream>>>(cnt, pos);
    k_scatter_embed<<<(NE + 255) / 256, 256, 0, stream>>>(ei, pos, dist, We, be, srcS, dstS, ebfS);

    for (int l = 0; l < NL; ++l) {
        k_message<<<NB_MSG, 256, 0, stream>>>(
            hbf, srcS, dstS, ebfS,
            W1f + (size_t)l * KA * HD, mb1 + l * HD,
            W2f + (size_t)l * HD * HD, mb2 + l * HD, agg);
        k_update<<<NN / 32, 256, 0, stream>>>(
            h, agg,
            U1f + (size_t)l * KU * HD, ub1 + l * HD,
            U2f + (size_t)l * HD * NF, ub2 + l * NF,
            lng + l * NF, lnb + l * NF, hbf);
    }
    k_out<<<(NN + 63) / 64, 256, 0, stream>>>(hbf, Wof, bo, (float*)d_out);
}

// Round 6
// 591.982 us; speedup vs baseline: 1.9494x; 1.9494x over previous
//
#include <hip/hip_runtime.h>

#define NN 20000
#define NE 640000
#define NF 128
#define EF 32
#define HD 128
#define NL 3

typedef __bf16 bf16x8 __attribute__((ext_vector_type(8)));
typedef float f32x4 __attribute__((ext_vector_type(4)));

constexpr int BE = 64;          // edges per k_message block
constexpr int KA = 2 * NF + EF; // 288
constexpr int SA2 = 168;        // sA row stride (bf16), 160 cols used
constexpr int STP = 136;        // sT / sM row stride (bf16)
constexpr int KU = NF + HD;     // 256
constexpr int SUP = 264;        // sU row stride (bf16), k_update
constexpr int SXP = 132;        // sX row stride (f32)
constexpr int NB_MSG = NE / BE; // 10000
constexpr int CPX = NB_MSG / 8; // 1250

// ================= fused pre: hist + weight repack + node embed =================
__global__ __launch_bounds__(256) void k_pre(
    const int* __restrict__ ei, int* __restrict__ cnt,
    const float* __restrict__ mW1, const float* __restrict__ mW2,
    const float* __restrict__ uW1, const float* __restrict__ uW2,
    const float* __restrict__ Wo,
    __bf16* __restrict__ W1f, __bf16* __restrict__ W2f,
    __bf16* __restrict__ U1f, __bf16* __restrict__ U2f,
    __bf16* __restrict__ Wof,
    const float* __restrict__ coords, const float* __restrict__ Wn,
    const float* __restrict__ bn, float* __restrict__ h, __bf16* __restrict__ hbf)
{
    const int b = blockIdx.x;
    const int tid = threadIdx.x;
    if (b < 2500) {
        const int e = b * 256 + tid;
        atomicAdd(&cnt[ei[NE + e]], 1);
        return;
    }
    if (b < 2564) {
        const int t = (b - 2500) * 256 + tid;
        const int stride = 64 * 256;
        for (int i = t; i < NL * KA * HD; i += stride) {
            const int l = i / (KA * HD);
            const int r = i - l * (KA * HD);
            const int k = r >> 7, n = r & 127;
            W1f[(size_t)l * KA * HD + ((((k >> 3) * HD) + n) << 3) + (k & 7)] = (__bf16)mW1[i];
        }
        for (int i = t; i < NL * HD * HD; i += stride) {
            const int l = i / (HD * HD);
            const int r = i - l * (HD * HD);
            const int k = r >> 7, n = r & 127;
            W2f[(size_t)l * HD * HD + ((((k >> 3) * HD) + n) << 3) + (k & 7)] = (__bf16)mW2[i];
        }
        for (int i = t; i < NL * KU * HD; i += stride) {
            const int l = i / (KU * HD);
            const int r = i - l * (KU * HD);
            const int k = r >> 7, n = r & 127;
            U1f[(size_t)l * KU * HD + ((((k >> 3) * HD) + n) << 3) + (k & 7)] = (__bf16)uW1[i];
        }
        for (int i = t; i < NL * HD * NF; i += stride) {
            const int l = i / (HD * NF);
            const int r = i - l * (HD * NF);
            const int k = r >> 7, n = r & 127;
            U2f[(size_t)l * HD * NF + ((((k >> 3) * NF) + n) << 3) + (k & 7)] = (__bf16)uW2[i];
        }
        for (int i = t; i < NF * HD; i += stride) {
            const int k = i >> 7, n = i & 127;
            Wof[((((k >> 3) * HD) + n) << 3) + (k & 7)] = (__bf16)Wo[i];
        }
        return;
    }
    // node embedding: 2 nodes per block
    __shared__ float sc[12];
    const int n0 = (b - 2564) * 2;
    if (tid < 12) sc[tid] = coords[n0 * 6 + tid];
    __syncthreads();
    const int node = n0 + (tid >> 7);
    const int f = tid & 127;
    const int cb = (tid >> 7) * 6;
    float acc = bn[f];
#pragma unroll
    for (int k = 0; k < 6; ++k) acc = fmaf(sc[cb + k], Wn[k * NF + f], acc);
    h[(size_t)node * NF + f] = acc;
    hbf[(size_t)node * NF + f] = (__bf16)acc;
}

// ================= exclusive scan of counts =================
__global__ __launch_bounds__(1024) void k_scan(const int* __restrict__ cnt, int* __restrict__ pos)
{
    __shared__ int ls[1024];
    const int tid = threadIdx.x;
    const int C = 20;
    const int base = tid * C;
    int s = 0;
#pragma unroll
    for (int i = 0; i < C; ++i) {
        const int idx = base + i;
        if (idx < NN) s += cnt[idx];
    }
    ls[tid] = s;
    __syncthreads();
    for (int off = 1; off < 1024; off <<= 1) {
        const int v = (tid >= off) ? ls[tid - off] : 0;
        __syncthreads();
        ls[tid] += v;
        __syncthreads();
    }
    int p = tid ? ls[tid - 1] : 0;
#pragma unroll
    for (int i = 0; i < C; ++i) {
        const int idx = base + i;
        if (idx < NN) { pos[idx] = p; p += cnt[idx]; }
    }
}

// ================= scatter edges to sorted order + fused edge embedding =================
__global__ __launch_bounds__(256) void k_scatter_embed(
    const int* __restrict__ ei, int* __restrict__ pos,
    const float* __restrict__ dist, const float* __restrict__ We,
    const float* __restrict__ be,
    int* __restrict__ srcS, int* __restrict__ dstS, __bf16* __restrict__ ebfS)
{
    __shared__ float sW[32][33];
    __shared__ float sbe[32];
    const int tid = threadIdx.x;
    for (int i = tid; i < 1024; i += 256) sW[i >> 5][i & 31] = We[i];
    if (tid < 32) sbe[tid] = be[tid];
    __syncthreads();
    const int e = blockIdx.x * 256 + tid;
    if (e >= NE) return;
    const int d = ei[NE + e];
    const int p = atomicAdd(&pos[d], 1);
    srcS[p] = ei[e];
    dstS[p] = d;
    float dr[32];
    const float4* dp = reinterpret_cast<const float4*>(dist + (size_t)e * EF);
#pragma unroll
    for (int q = 0; q < 8; ++q) {
        const float4 v = dp[q];
        dr[q * 4 + 0] = v.x; dr[q * 4 + 1] = v.y; dr[q * 4 + 2] = v.z; dr[q * 4 + 3] = v.w;
    }
#pragma unroll
    for (int jg = 0; jg < 4; ++jg) {
        union { __bf16 b[8]; uint4 u; } pk;
#pragma unroll
        for (int jj = 0; jj < 8; ++jj) {
            const int j = jg * 8 + jj;
            float acc = sbe[j];
#pragma unroll
            for (int q = 0; q < 32; ++q) acc = fmaf(dr[q], sW[q][j], acc);
            pk.b[jj] = (__bf16)acc;
        }
        *reinterpret_cast<uint4*>(ebfS + (size_t)p * EF + jg * 8) = pk.u;
    }
}

// ================= fused edge message (bf16 MFMA, two-pass K) + segmented scatter =================
// launch_bounds (256,6): VGPR cap 85. B-fragments loaded JIT in the MFMA loops
// (L1-hot weights) so natural demand ~70 regs -> no spill. LDS 22KB -> 6-7 blk/CU.
__global__ __launch_bounds__(256, 6) void k_message(
    const __bf16* __restrict__ hbf,
    const int* __restrict__ srcS, const int* __restrict__ dstS,
    const __bf16* __restrict__ ebfS,
    const __bf16* __restrict__ W1f, const float* __restrict__ b1,
    const __bf16* __restrict__ W2f, const float* __restrict__ b2,
    float* __restrict__ agg)
{
    __shared__ __attribute__((aligned(16))) __bf16 R[BE * SA2]; // sA(64x168) -> sT(64x136) -> sM(64x136)
    __shared__ int s_src[BE], s_dst[BE];
    __bf16* sA = R;
    __bf16* sT = R;
    __bf16* sM = R;

    const int tid = threadIdx.x;
    const int bid = (blockIdx.x & 7) * CPX + (blockIdx.x >> 3); // XCD chunk swizzle
    const int e0 = bid * BE;
    const int w = tid >> 6;
    const int lane = tid & 63;
    const int m16 = lane & 15;
    const int kb = lane >> 4;
    const int n0 = w * 32;

    if (tid < BE) {
        s_src[tid] = srcS[e0 + tid];
        s_dst[tid] = dstS[e0 + tid];
    }
    __syncthreads();

    // ---- gather pass 1: sA[row][0:128] = h[src], sA[row][128:160] = e ----
#pragma unroll
    for (int it = 0; it < 4; ++it) {
        const int c = tid + it * 256;
        const int row = c >> 4, off = c & 15;
        *reinterpret_cast<uint4*>(&sA[row * SA2 + off * 8]) =
            *reinterpret_cast<const uint4*>(hbf + (size_t)s_src[row] * NF + off * 8);
    }
    {
        const int row = tid >> 2, off = tid & 3;
        *reinterpret_cast<uint4*>(&sA[row * SA2 + NF + off * 8]) =
            *reinterpret_cast<const uint4*>(ebfS + (size_t)(e0 + row) * EF + off * 8);
    }
    __syncthreads();

    // ---- GEMM1 pass A: K-blocks {0,1,2,3,8} ----
    f32x4 acc1[4][2];
#pragma unroll
    for (int mt = 0; mt < 4; ++mt)
#pragma unroll
        for (int nf = 0; nf < 2; ++nf) acc1[mt][nf] = (f32x4){0.f, 0.f, 0.f, 0.f};

    __builtin_amdgcn_s_setprio(1);
#pragma unroll
    for (int k5 = 0; k5 < 5; ++k5) {
        const int wb = (k5 < 4) ? k5 : 8;
        const bf16x8 bA = *reinterpret_cast<const bf16x8*>(W1f + ((((wb * 4 + kb) * HD) + n0 + m16) << 3));
        const bf16x8 bB = *reinterpret_cast<const bf16x8*>(W1f + ((((wb * 4 + kb) * HD) + n0 + 16 + m16) << 3));
#pragma unroll
        for (int mt = 0; mt < 4; ++mt) {
            const bf16x8 a = *reinterpret_cast<const bf16x8*>(&sA[(mt * 16 + m16) * SA2 + k5 * 32 + kb * 8]);
            acc1[mt][0] = __builtin_amdgcn_mfma_f32_16x16x32_bf16(a, bA, acc1[mt][0], 0, 0, 0);
            acc1[mt][1] = __builtin_amdgcn_mfma_f32_16x16x32_bf16(a, bB, acc1[mt][1], 0, 0, 0);
        }
    }
    __builtin_amdgcn_s_setprio(0);
    __syncthreads(); // pass-1 sA reads done

    // ---- gather pass 2: sA[row][0:128] = h[dst] ----
#pragma unroll
    for (int it = 0; it < 4; ++it) {
        const int c = tid + it * 256;
        const int row = c >> 4, off = c & 15;
        *reinterpret_cast<uint4*>(&sA[row * SA2 + off * 8]) =
            *reinterpret_cast<const uint4*>(hbf + (size_t)s_dst[row] * NF + off * 8);
    }
    __syncthreads();

    // ---- GEMM1 pass B: K-blocks {4,5,6,7} ----
    __builtin_amdgcn_s_setprio(1);
#pragma unroll
    for (int k4 = 0; k4 < 4; ++k4) {
        const int wb = 4 + k4;
        const bf16x8 bA = *reinterpret_cast<const bf16x8*>(W1f + ((((wb * 4 + kb) * HD) + n0 + m16) << 3));
        const bf16x8 bB = *reinterpret_cast<const bf16x8*>(W1f + ((((wb * 4 + kb) * HD) + n0 + 16 + m16) << 3));
#pragma unroll
        for (int mt = 0; mt < 4; ++mt) {
            const bf16x8 a = *reinterpret_cast<const bf16x8*>(&sA[(mt * 16 + m16) * SA2 + k4 * 32 + kb * 8]);
            acc1[mt][0] = __builtin_amdgcn_mfma_f32_16x16x32_bf16(a, bA, acc1[mt][0], 0, 0, 0);
            acc1[mt][1] = __builtin_amdgcn_mfma_f32_16x16x32_bf16(a, bB, acc1[mt][1], 0, 0, 0);
        }
    }
    __builtin_amdgcn_s_setprio(0);
    __syncthreads(); // pass-2 sA reads done

    // ---- sT = relu(acc1 + b1) ----
    {
        const float b1a = b1[n0 + m16];
        const float b1b = b1[n0 + 16 + m16];
#pragma unroll
        for (int mt = 0; mt < 4; ++mt) {
#pragma unroll
            for (int reg = 0; reg < 4; ++reg) {
                const int erow = mt * 16 + kb * 4 + reg;
                sT[erow * STP + n0 + m16] = (__bf16)fmaxf(acc1[mt][0][reg] + b1a, 0.f);
                sT[erow * STP + n0 + 16 + m16] = (__bf16)fmaxf(acc1[mt][1][reg] + b1b, 0.f);
            }
        }
    }
    __syncthreads();

    // ---- GEMM2 ----
    f32x4 acc2[4][2];
#pragma unroll
    for (int mt = 0; mt < 4; ++mt)
#pragma unroll
        for (int nf = 0; nf < 2; ++nf) acc2[mt][nf] = (f32x4){0.f, 0.f, 0.f, 0.f};

    __builtin_amdgcn_s_setprio(1);
#pragma unroll
    for (int k4 = 0; k4 < 4; ++k4) {
        const bf16x8 bA = *reinterpret_cast<const bf16x8*>(W2f + ((((k4 * 4 + kb) * HD) + n0 + m16) << 3));
        const bf16x8 bB = *reinterpret_cast<const bf16x8*>(W2f + ((((k4 * 4 + kb) * HD) + n0 + 16 + m16) << 3));
#pragma unroll
        for (int mt = 0; mt < 4; ++mt) {
            const bf16x8 a = *reinterpret_cast<const bf16x8*>(&sT[(mt * 16 + m16) * STP + k4 * 32 + kb * 8]);
            acc2[mt][0] = __builtin_amdgcn_mfma_f32_16x16x32_bf16(a, bA, acc2[mt][0], 0, 0, 0);
            acc2[mt][1] = __builtin_amdgcn_mfma_f32_16x16x32_bf16(a, bB, acc2[mt][1], 0, 0, 0);
        }
    }
    __builtin_amdgcn_s_setprio(0);
    __syncthreads(); // sT reads done

    // ---- sM = acc2 + b2 (bf16) ----
    {
        const float b2a = b2[n0 + m16];
        const float b2b = b2[n0 + 16 + m16];
#pragma unroll
        for (int mt = 0; mt < 4; ++mt) {
#pragma unroll
            for (int reg = 0; reg < 4; ++reg) {
                const int erow = mt * 16 + kb * 4 + reg;
                sM[erow * STP + n0 + m16] = (__bf16)(acc2[mt][0][reg] + b2a);
                sM[erow * STP + n0 + 16 + m16] = (__bf16)(acc2[mt][1][reg] + b2b);
            }
        }
    }
    __syncthreads();

    // ---- segmented reduction over dst-sorted rows ----
    {
        const int col = tid & 127;
        const int r0 = (tid >> 7) * 32;
        int cur = s_dst[r0];
        float s = (float)sM[r0 * STP + col];
#pragma unroll
        for (int r = r0 + 1; r < r0 + 32; ++r) {
            const int d2 = s_dst[r];
            const float v = (float)sM[r * STP + col];
            if (d2 != cur) {
                atomicAdd(&agg[(size_t)cur * HD + col], s);
                cur = d2;
                s = v;
            } else {
                s += v;
            }
        }
        atomicAdd(&agg[(size_t)cur * HD + col], s);
    }
}

// ================= node update MLP (bf16 MFMA) + residual + LayerNorm, 32-node tiles =================
__global__ __launch_bounds__(256, 8) void k_update(
    float* __restrict__ h, float* __restrict__ agg,
    const __bf16* __restrict__ U1f, const float* __restrict__ b1,
    const __bf16* __restrict__ U2f, const float* __restrict__ b2,
    const float* __restrict__ g, const float* __restrict__ bln,
    __bf16* __restrict__ hbf)
{
    __shared__ __attribute__((aligned(16))) __bf16 R[32 * SUP]; // sU(32x264) / sT(32x136) / sX f32(32x132)
    __bf16* sU = R;
    __bf16* sT = R;
    float* sX = (float*)R;

    const int tid = threadIdx.x;
    const int n0 = blockIdx.x * 32;
    const int w = tid >> 6;
    const int lane = tid & 63;
    const int m16 = lane & 15;
    const int kb = lane >> 4;
    const int nw0 = w * 32;

#pragma unroll
    for (int it = 0; it < 2; ++it) {
        const int c = tid + it * 256;
        const int row = c >> 4, off = c & 15;
        *reinterpret_cast<uint4*>(&sU[row * SUP + off * 8]) =
            *reinterpret_cast<const uint4*>(hbf + (size_t)(n0 + row) * NF + off * 8);
    }
#pragma unroll
    for (int it = 0; it < 4; ++it) {
        const int c = tid + it * 256;
        const int row = c >> 5, off = c & 31;
        float* ap = agg + (size_t)(n0 + row) * HD + off * 4;
        const float4 v = *reinterpret_cast<const float4*>(ap);
        union { __bf16 b[4]; uint2 u; } cv;
        cv.b[0] = (__bf16)v.x; cv.b[1] = (__bf16)v.y; cv.b[2] = (__bf16)v.z; cv.b[3] = (__bf16)v.w;
        *reinterpret_cast<uint2*>(&sU[row * SUP + NF + off * 4]) = cv.u;
        *reinterpret_cast<float4*>(ap) = (float4){0.f, 0.f, 0.f, 0.f};
    }
    __syncthreads();

    f32x4 acc1[2][2];
#pragma unroll
    for (int mt = 0; mt < 2; ++mt)
#pragma unroll
        for (int nf = 0; nf < 2; ++nf) acc1[mt][nf] = (f32x4){0.f, 0.f, 0.f, 0.f};
#pragma unroll
    for (int k8 = 0; k8 < 8; ++k8) {
        const bf16x8 bA = *reinterpret_cast<const bf16x8*>(U1f + ((((k8 * 4 + kb) * HD) + nw0 + m16) << 3));
        const bf16x8 bB = *reinterpret_cast<const bf16x8*>(U1f + ((((k8 * 4 + kb) * HD) + nw0 + 16 + m16) << 3));
#pragma unroll
        for (int mt = 0; mt < 2; ++mt) {
            const bf16x8 a = *reinterpret_cast<const bf16x8*>(&sU[(mt * 16 + m16) * SUP + k8 * 32 + kb * 8]);
            acc1[mt][0] = __builtin_amdgcn_mfma_f32_16x16x32_bf16(a, bA, acc1[mt][0], 0, 0, 0);
            acc1[mt][1] = __builtin_amdgcn_mfma_f32_16x16x32_bf16(a, bB, acc1[mt][1], 0, 0, 0);
        }
    }
    __syncthreads();

    {
        const float b1a = b1[nw0 + m16];
        const float b1b = b1[nw0 + 16 + m16];
#pragma unroll
        for (int mt = 0; mt < 2; ++mt) {
#pragma unroll
            for (int reg = 0; reg < 4; ++reg) {
                const int erow = mt * 16 + kb * 4 + reg;
                sT[erow * STP + nw0 + m16] = (__bf16)fmaxf(acc1[mt][0][reg] + b1a, 0.f);
                sT[erow * STP + nw0 + 16 + m16] = (__bf16)fmaxf(acc1[mt][1][reg] + b1b, 0.f);
            }
        }
    }
    __syncthreads();

    f32x4 acc2[2][2];
#pragma unroll
    for (int mt = 0; mt < 2; ++mt)
#pragma unroll
        for (int nf = 0; nf < 2; ++nf) acc2[mt][nf] = (f32x4){0.f, 0.f, 0.f, 0.f};
#pragma unroll
    for (int k4 = 0; k4 < 4; ++k4) {
        const bf16x8 bA = *reinterpret_cast<const bf16x8*>(U2f + ((((k4 * 4 + kb) * NF) + nw0 + m16) << 3));
        const bf16x8 bB = *reinterpret_cast<const bf16x8*>(U2f + ((((k4 * 4 + kb) * NF) + nw0 + 16 + m16) << 3));
#pragma unroll
        for (int mt = 0; mt < 2; ++mt) {
            const bf16x8 a = *reinterpret_cast<const bf16x8*>(&sT[(mt * 16 + m16) * STP + k4 * 32 + kb * 8]);
            acc2[mt][0] = __builtin_amdgcn_mfma_f32_16x16x32_bf16(a, bA, acc2[mt][0], 0, 0, 0);
            acc2[mt][1] = __builtin_amdgcn_mfma_f32_16x16x32_bf16(a, bB, acc2[mt][1], 0, 0, 0);
        }
    }
    __syncthreads();

    {
        const float b2a = b2[nw0 + m16];
        const float b2b = b2[nw0 + 16 + m16];
#pragma unroll
        for (int mt = 0; mt < 2; ++mt) {
#pragma unroll
            for (int reg = 0; reg < 4; ++reg) {
                const int erow = mt * 16 + kb * 4 + reg;
                const size_t base = (size_t)(n0 + erow) * NF;
                sX[erow * SXP + nw0 + m16] = h[base + nw0 + m16] + acc2[mt][0][reg] + b2a;
                sX[erow * SXP + nw0 + 16 + m16] = h[base + nw0 + 16 + m16] + acc2[mt][1][reg] + b2b;
            }
        }
    }
    __syncthreads();

    {
        const int i = tid >> 3, j = tid & 7;
        float s = 0.f, s2 = 0.f;
#pragma unroll
        for (int t = 0; t < 16; ++t) {
            const float x = sX[i * SXP + j + 8 * t];
            s += x; s2 = fmaf(x, x, s2);
        }
        s += __shfl_xor(s, 1, 64);  s2 += __shfl_xor(s2, 1, 64);
        s += __shfl_xor(s, 2, 64);  s2 += __shfl_xor(s2, 2, 64);
        s += __shfl_xor(s, 4, 64);  s2 += __shfl_xor(s2, 4, 64);
        const float mu = s * (1.f / NF);
        const float var = s2 * (1.f / NF) - mu * mu;
        const float rs = rsqrtf(var + 1e-5f);
        const size_t base = (size_t)(n0 + i) * NF;
#pragma unroll
        for (int t = 0; t < 16; ++t) {
            const int col = j + 8 * t;
            const float v = (sX[i * SXP + col] - mu) * rs * g[col] + bln[col];
            h[base + col] = v;
            hbf[base + col] = (__bf16)v;
        }
    }
}

// ================= output projection (bf16 MFMA) =================
__global__ __launch_bounds__(256, 4) void k_out(
    const __bf16* __restrict__ hbf, const __bf16* __restrict__ Wof,
    const float* __restrict__ bo, float* __restrict__ out)
{
    __shared__ __attribute__((aligned(16))) __bf16 sH[64 * STP];
    const int tid = threadIdx.x;
    const int n0 = blockIdx.x * 64;
    const int w = tid >> 6;
    const int lane = tid & 63;
    const int m16 = lane & 15;
    const int kb = lane >> 4;
    const int nw0 = w * 32;

#pragma unroll
    for (int it = 0; it < 4; ++it) {
        const int c = tid + it * 256;
        const int row = c >> 4, off = c & 15;
        const int node = min(n0 + row, NN - 1);
        *reinterpret_cast<uint4*>(&sH[row * STP + off * 8]) =
            *reinterpret_cast<const uint4*>(hbf + (size_t)node * NF + off * 8);
    }
    __syncthreads();

    f32x4 acc[4][2];
#pragma unroll
    for (int mt = 0; mt < 4; ++mt)
#pragma unroll
        for (int nf = 0; nf < 2; ++nf) acc[mt][nf] = (f32x4){0.f, 0.f, 0.f, 0.f};
#pragma unroll
    for (int k4 = 0; k4 < 4; ++k4) {
        const bf16x8 bA = *reinterpret_cast<const bf16x8*>(Wof + ((((k4 * 4 + kb) * HD) + nw0 + m16) << 3));
        const bf16x8 bB = *reinterpret_cast<const bf16x8*>(Wof + ((((k4 * 4 + kb) * HD) + nw0 + 16 + m16) << 3));
#pragma unroll
        for (int mt = 0; mt < 4; ++mt) {
            const bf16x8 a = *reinterpret_cast<const bf16x8*>(&sH[(mt * 16 + m16) * STP + k4 * 32 + kb * 8]);
            acc[mt][0] = __builtin_amdgcn_mfma_f32_16x16x32_bf16(a, bA, acc[mt][0], 0, 0, 0);
            acc[mt][1] = __builtin_amdgcn_mfma_f32_16x16x32_bf16(a, bB, acc[mt][1], 0, 0, 0);
        }
    }
    const float boa = bo[nw0 + m16];
    const float bob = bo[nw0 + 16 + m16];
#pragma unroll
    for (int mt = 0; mt < 4; ++mt) {
#pragma unroll
        for (int reg = 0; reg < 4; ++reg) {
            const int erow = mt * 16 + kb * 4 + reg;
            const int node = n0 + erow;
            if (node < NN) {
                out[(size_t)node * HD + nw0 + m16] = acc[mt][0][reg] + boa;
                out[(size_t)node * HD + nw0 + 16 + m16] = acc[mt][1][reg] + bob;
            }
        }
    }
}

extern "C" void kernel_launch(void* const* d_in, const int* in_sizes, int n_in,
                              void* d_out, int out_size, void* d_ws, size_t ws_size,
                              hipStream_t stream)
{
    const float* coords = (const float*)d_in[0];
    const int* ei       = (const int*)d_in[1];
    const float* dist   = (const float*)d_in[2];
    const float* Wn  = (const float*)d_in[3];
    const float* bn  = (const float*)d_in[4];
    const float* We  = (const float*)d_in[5];
    const float* be  = (const float*)d_in[6];
    const float* mW1 = (const float*)d_in[7];
    const float* mb1 = (const float*)d_in[8];
    const float* mW2 = (const float*)d_in[9];
    const float* mb2 = (const float*)d_in[10];
    const float* uW1 = (const float*)d_in[11];
    const float* ub1 = (const float*)d_in[12];
    const float* uW2 = (const float*)d_in[13];
    const float* ub2 = (const float*)d_in[14];
    const float* lng = (const float*)d_in[15];
    const float* lnb = (const float*)d_in[16];
    const float* Wo  = (const float*)d_in[17];
    const float* bo  = (const float*)d_in[18];

    char* p = (char*)d_ws;
    float* h   = (float*)p; p += (size_t)NN * NF * 4;
    float* agg = (float*)p; p += (size_t)NN * NF * 4;
    __bf16* hbf  = (__bf16*)p; p += (size_t)NN * NF * 2;
    __bf16* ebfS = (__bf16*)p; p += (size_t)NE * EF * 2;
    __bf16* W1f = (__bf16*)p; p += (size_t)NL * KA * HD * 2;
    __bf16* W2f = (__bf16*)p; p += (size_t)NL * HD * HD * 2;
    __bf16* U1f = (__bf16*)p; p += (size_t)NL * KU * HD * 2;
    __bf16* U2f = (__bf16*)p; p += (size_t)NL * HD * NF * 2;
    __bf16* Wof = (__bf16*)p; p += (size_t)NF * HD * 2;
    int* cnt  = (int*)p; p += (size_t)NN * 4;
    int* pos  = (int*)p; p += (size_t)NN * 4;
    int* srcS = (int*)p; p += (size_t)NE * 4;
    int* dstS = (int*)p; p += (size_t)NE * 4;

    hipMemsetAsync(cnt, 0, (size_t)NN * 4, stream);
    hipMemsetAsync(agg, 0, (size_t)NN * NF * sizeof(float), stream);

    k_pre<<<2564 + NN / 2, 256, 0, stream>>>(ei, cnt, mW1, mW2, uW1, uW2, Wo,
                                             W1f, W2f, U1f, U2f, Wof,
                                             coords, Wn, bn, h, hbf);
    k_scan<<<1, 1024, 0, stream>>>(cnt, pos);
    k_scatter_embed<<<(NE + 255) / 256, 256, 0, stream>>>(ei, pos, dist, We, be, srcS, dstS, ebfS);

    for (int l = 0; l < NL; ++l) {
        k_message<<<NB_MSG, 256, 0, stream>>>(
            hbf, srcS, dstS, ebfS,
            W1f + (size_t)l * KA * HD, mb1 + l * HD,
            W2f + (size_t)l * HD * HD, mb2 + l * HD, agg);
        k_update<<<NN / 32, 256, 0, stream>>>(
            h, agg,
            U1f + (size_t)l * KU * HD, ub1 + l * HD,
            U2f + (size_t)l * HD * NF, ub2 + l * NF,
            lng + l * NF, lnb + l * NF, hbf);
    }
    k_out<<<(NN + 63) / 64, 256, 0, stream>>>(hbf, Wof, bo, (float*)d_out);
}